// Round 25
// baseline (221.529 us; speedup 1.0000x reference)
//
#include <hip/hip_runtime.h>
#include <cstdint>

#define CC 32
#define DD 9
#define CD 288   // C*D
#define BB 8
#define HH 64
#define ZZ 4
#define NB 8     // nodes per batch in node-side kernels

typedef __attribute__((ext_vector_type(8))) short bf16x8;
typedef __attribute__((ext_vector_type(4))) float f32x4;
typedef __attribute__((ext_vector_type(2))) float f32x2;

__device__ __forceinline__ float silu_f(float v) {
  return v / (1.0f + __expf(-v));
}

__device__ __forceinline__ int blk_of(int d) { return d == 0 ? 0 : (d < 4 ? 1 : 2); }

__device__ __forceinline__ unsigned int f2bf(float f) {   // round-to-nearest-even
  unsigned int u = __float_as_uint(f);
  return (u + 0x7fffu + ((u >> 16) & 1u)) >> 16;
}
__device__ __forceinline__ float bf_lo(unsigned int u) { return __uint_as_float(u << 16); }
__device__ __forceinline__ float bf_hi(unsigned int u) { return __uint_as_float(u & 0xffff0000u); }

__global__ __launch_bounds__(256) void k_zero(float* __restrict__ p, int n) {
  int i = blockIdx.x * 256 + threadIdx.x;
  if (i < n) p[i] = 0.0f;
}

// ---------------- CSR build ----------------
__global__ __launch_bounds__(256) void k_hist(const int* __restrict__ edst,
                                              int* __restrict__ deg, int E) {
  int e = blockIdx.x * 256 + threadIdx.x;
  if (e < E) atomicAdd(&deg[edst[e]], 1);
}

__global__ __launch_bounds__(1024) void k_scan(const int* __restrict__ deg,
                                               int* __restrict__ offs,
                                               int* __restrict__ cursor, int N) {
  __shared__ int part[1024];
  int t = threadIdx.x;
  int chunk = (N + 1023) >> 10;
  int base = t * chunk;
  int lim = N - base; if (lim > chunk) lim = chunk; if (lim < 0) lim = 0;
  int s = 0;
  for (int i = 0; i < lim; ++i) s += deg[base + i];
  part[t] = s;
  __syncthreads();
  for (int off = 1; off < 1024; off <<= 1) {
    int v = part[t];
    int u = (t >= off) ? part[t - off] : 0;
    __syncthreads();
    part[t] = v + u;
    __syncthreads();
  }
  int run = (t == 0) ? 0 : part[t - 1];
  for (int i = 0; i < lim; ++i) {
    offs[base + i] = run;
    cursor[base + i] = run;
    run += deg[base + i];
  }
  if (t == 1023) offs[N] = run;
}

// scatter + fused esh packing: eidx[pos], srcs[pos], esh_p[pos*5 + 0..4]
__global__ __launch_bounds__(256) void k_scatter(const int* __restrict__ edst,
                                                 const int* __restrict__ esrc,
                                                 const float* __restrict__ esh,
                                                 int* __restrict__ cursor,
                                                 int* __restrict__ eidx,
                                                 int* __restrict__ srcs,
                                                 unsigned int* __restrict__ esh_p, int E) {
  int e = blockIdx.x * 256 + threadIdx.x;
  if (e < E) {
    int d = edst[e];
    int pos = atomicAdd(&cursor[d], 1);
    eidx[pos] = e;
    srcs[pos] = esrc[e];
    const float* sp = esh + (size_t)e * 9;
    unsigned int* op = esh_p + (size_t)pos * 5;
#pragma unroll
    for (int jj = 0; jj < 5; ++jj) {
      unsigned int lo = f2bf(sp[2 * jj]);
      unsigned int hi = (jj < 4) ? f2bf(sp[2 * jj + 1]) : 0u;
      op[jj] = lo | (hi << 16);
    }
  }
}

// ---------------- linear_up: persistent blocks + register prefetch ----------------
__global__ __launch_bounds__(288, 1) void k_linear_up(
    const float* __restrict__ nf, const float* __restrict__ Wup,
    unsigned int* __restrict__ x_p, int N) {
  __shared__ float snf[NB][DD * 36];
  __shared__ float sval[NB][DD][CC];
  int t = threadIdx.x;
  int g = t >> 5, q = t & 31;
  int tc = t / 9, td = t - tc * 9;
  int l0 = blk_of(g);
  float wcol[CC];
#pragma unroll
  for (int c = 0; c < CC; ++c) wcol[c] = Wup[l0 * 1024 + c * 32 + q];
  int nbat = (N + NB - 1) / NB;
  int b = blockIdx.x;
  float r[NB];
  if (b < nbat) {
#pragma unroll
    for (int nb = 0; nb < NB; ++nb) {
      int n = b * NB + nb; if (n >= N) n = N - 1;
      r[nb] = nf[(size_t)n * CD + t];
    }
  }
  for (; b < nbat; b += gridDim.x) {
    int n0 = b * NB;
    __syncthreads();
#pragma unroll
    for (int nb = 0; nb < NB; ++nb) snf[nb][td * 36 + tc] = r[nb];
    __syncthreads();
    int b2 = b + gridDim.x;
    if (b2 < nbat) {
#pragma unroll
      for (int nb = 0; nb < NB; ++nb) {
        int n = b2 * NB + nb; if (n >= N) n = N - 1;
        r[nb] = nf[(size_t)n * CD + t];
      }
    }
#pragma unroll
    for (int nb = 0; nb < NB; ++nb) {
      const float4* rowp = (const float4*)(snf[nb] + g * 36);
      float a0 = 0.f, a1 = 0.f;
#pragma unroll
      for (int c4 = 0; c4 < 8; ++c4) {
        float4 bb = rowp[c4];
        a0 += bb.x * wcol[c4 * 4 + 0] + bb.y * wcol[c4 * 4 + 1];
        a1 += bb.z * wcol[c4 * 4 + 2] + bb.w * wcol[c4 * 4 + 3];
      }
      sval[nb][g][q] = a0 + a1;
    }
    __syncthreads();
#pragma unroll
    for (int it = 0; it < 5; ++it) {
      int idx = it * 288 + t;
      if (idx < NB * 160) {
        int nb = idx / 160, rr = idx - nb * 160;
        int p = rr >> 5, c = rr & 31;
        if (n0 + nb < N) {
          unsigned int lo = f2bf(sval[nb][2 * p][c]);
          unsigned int hi = (p < 4) ? f2bf(sval[nb][2 * p + 1][c]) : 0u;
          x_p[(size_t)(n0 + nb) * 160 + rr] = lo | (hi << 16);
        }
      }
    }
  }
}

// ---------------- radial MLP: ALL THREE layers via MFMA; one wave = 64 edges ----------------
__global__ __launch_bounds__(64) void k_mlp_mfma(
    const float* __restrict__ ef, const float* __restrict__ cut,
    const float* __restrict__ W1, const float* __restrict__ W2,
    const float* __restrict__ W3, const int* __restrict__ eidx,
    unsigned int* __restrict__ w_p, int E) {
  __shared__ ushort efbuf[2048];   // 4KB B-frag for layer1
  __shared__ ushort buf[4096];     // 8KB h1 then h2
  __shared__ float scut[64];
  int l = threadIdx.x;
  int h = l >> 4, li = l & 15;
  bf16x8 A1[4];
#pragma unroll
  for (int qm = 0; qm < 4; ++qm)
#pragma unroll
    for (int j = 0; j < 8; ++j)
      A1[qm][j] = (h == 0) ? (short)f2bf(W1[j * HH + 16 * qm + li]) : (short)0;
  bf16x8 A2[4][2];
#pragma unroll
  for (int qm = 0; qm < 4; ++qm)
#pragma unroll
    for (int kb = 0; kb < 2; ++kb)
#pragma unroll
      for (int j = 0; j < 8; ++j)
        A2[qm][kb][j] = (short)f2bf(W2[(32 * kb + 8 * h + j) * HH + 16 * qm + li]);
  bf16x8 A3[2][2];
#pragma unroll
  for (int cm = 0; cm < 2; ++cm)
#pragma unroll
    for (int kb = 0; kb < 2; ++kb)
#pragma unroll
      for (int j = 0; j < 8; ++j)
        A3[cm][kb][j] = (short)f2bf(W3[(32 * kb + 8 * h + j) * CC + 16 * cm + li]);
#pragma unroll
  for (int i = 0; i < 16; ++i) ((unsigned int*)efbuf)[i * 64 + l] = 0u;

  int ntile = E >> 6;
  for (int tile = blockIdx.x; tile < ntile; tile += gridDim.x) {
    int pos = tile * 64 + l;
    int eo = eidx[pos];
    const float4* efp = (const float4*)(ef + (size_t)eo * BB);
    float4 efa = efp[0];
    float4 efb = efp[1];
    scut[l] = cut[eo];
    {
      unsigned int d0 = f2bf(efa.x) | (f2bf(efa.y) << 16);
      unsigned int d1 = f2bf(efa.z) | (f2bf(efa.w) << 16);
      unsigned int d2 = f2bf(efb.x) | (f2bf(efb.y) << 16);
      unsigned int d3 = f2bf(efb.z) | (f2bf(efb.w) << 16);
      *(uint4*)&efbuf[(((l >> 4) * 4) * 16 + (l & 15)) * 8] = make_uint4(d0, d1, d2, d3);
    }
    f32x4 acc1[4][4];
#pragma unroll
    for (int qm = 0; qm < 4; ++qm)
#pragma unroll
      for (int nb = 0; nb < 4; ++nb) acc1[qm][nb] = (f32x4){0.f, 0.f, 0.f, 0.f};
#pragma unroll
    for (int nb = 0; nb < 4; ++nb) {
      bf16x8 Bf = *(const bf16x8*)&efbuf[((nb * 4 + h) * 16 + li) * 8];
#pragma unroll
      for (int qm = 0; qm < 4; ++qm)
        acc1[qm][nb] = __builtin_amdgcn_mfma_f32_16x16x32_bf16(
            A1[qm], Bf, acc1[qm][nb], 0, 0, 0);
    }
#pragma unroll
    for (int qm = 0; qm < 4; ++qm)
#pragma unroll
      for (int nb = 0; nb < 4; ++nb) {
        float v0 = silu_f(acc1[qm][nb][0]);
        float v1 = silu_f(acc1[qm][nb][1]);
        float v2 = silu_f(acc1[qm][nb][2]);
        float v3 = silu_f(acc1[qm][nb][3]);
        unsigned int lo = f2bf(v0) | (f2bf(v1) << 16);
        unsigned int hi = f2bf(v2) | (f2bf(v3) << 16);
        int G = (nb * 2 + (qm >> 1)) * 4 + ((2 * qm + (h >> 1)) & 3);
        *(uint2*)&buf[(G * 16 + li) * 8 + (h & 1) * 4] = make_uint2(lo, hi);
      }
    f32x4 acc2[4][4];
#pragma unroll
    for (int qm = 0; qm < 4; ++qm)
#pragma unroll
      for (int nb = 0; nb < 4; ++nb) acc2[qm][nb] = (f32x4){0.f, 0.f, 0.f, 0.f};
#pragma unroll
    for (int nb = 0; nb < 4; ++nb)
#pragma unroll
      for (int kb = 0; kb < 2; ++kb) {
        int F = (nb * 2 + kb) * 4 + h;
        bf16x8 Bf = *(const bf16x8*)&buf[(F * 16 + li) * 8];
#pragma unroll
        for (int qm = 0; qm < 4; ++qm)
          acc2[qm][nb] = __builtin_amdgcn_mfma_f32_16x16x32_bf16(
              A2[qm][kb], Bf, acc2[qm][nb], 0, 0, 0);
      }
#pragma unroll
    for (int qm = 0; qm < 4; ++qm)
#pragma unroll
      for (int nb = 0; nb < 4; ++nb) {
        float v0 = silu_f(acc2[qm][nb][0]);
        float v1 = silu_f(acc2[qm][nb][1]);
        float v2 = silu_f(acc2[qm][nb][2]);
        float v3 = silu_f(acc2[qm][nb][3]);
        unsigned int lo = f2bf(v0) | (f2bf(v1) << 16);
        unsigned int hi = f2bf(v2) | (f2bf(v3) << 16);
        int G = (nb * 2 + (qm >> 1)) * 4 + ((2 * qm + (h >> 1)) & 3);
        *(uint2*)&buf[(G * 16 + li) * 8 + (h & 1) * 4] = make_uint2(lo, hi);
      }
    f32x4 acc3[2][4];
#pragma unroll
    for (int cm = 0; cm < 2; ++cm)
#pragma unroll
      for (int nb = 0; nb < 4; ++nb) acc3[cm][nb] = (f32x4){0.f, 0.f, 0.f, 0.f};
#pragma unroll
    for (int nb = 0; nb < 4; ++nb)
#pragma unroll
      for (int kb = 0; kb < 2; ++kb) {
        int G = (nb * 2 + kb) * 4 + h;
        bf16x8 Bf = *(const bf16x8*)&buf[(G * 16 + li) * 8];
#pragma unroll
        for (int cm = 0; cm < 2; ++cm)
          acc3[cm][nb] = __builtin_amdgcn_mfma_f32_16x16x32_bf16(
              A3[cm][kb], Bf, acc3[cm][nb], 0, 0, 0);
      }
#pragma unroll
    for (int nb = 0; nb < 4; ++nb) {
      float cv = scut[16 * nb + li];
#pragma unroll
      for (int cm = 0; cm < 2; ++cm) {
        unsigned int lo = f2bf(acc3[cm][nb][0] * cv) | (f2bf(acc3[cm][nb][1] * cv) << 16);
        unsigned int hi = f2bf(acc3[cm][nb][2] * cv) | (f2bf(acc3[cm][nb][3] * cv) << 16);
        *(uint2*)&w_p[(size_t)(tile * 64 + 16 * nb + li) * 16 + 8 * cm + 2 * h] =
            make_uint2(lo, hi);
      }
    }
  }
}

// ---------------- gather v9: 4-edge iteration, depth-2 register pipeline ----------------
struct Stage {
  bool ok;
  unsigned int wu;
  unsigned int shd[5];
  unsigned int xd[5];
};

__global__ __launch_bounds__(256) void k_gather(
    const unsigned int* __restrict__ x_p, const unsigned int* __restrict__ w_p,
    const unsigned int* __restrict__ esh_p, const float* __restrict__ CG,
    const int* __restrict__ offs, const int* __restrict__ srcs,
    float* __restrict__ mpre, int N) {
  int wid = (blockIdx.x * 256 + threadIdx.x) >> 6;
  if (wid >= N) return;
  int lane = threadIdx.x & 63;
  int h = lane >> 5, c = lane & 31;
  int beg = offs[wid], end = offs[wid + 1];
  f32x2 Pp[36];
  float P8[9];
#pragma unroll
  for (int i = 0; i < 36; ++i) Pp[i] = (f32x2){0.f, 0.f};
#pragma unroll
  for (int i = 0; i < 9; ++i) P8[i] = 0.f;

  auto loadStage = [&](int p) {
    Stage s;
    s.ok = p < end;
    int pp = s.ok ? p : beg;
    int sidx = srcs[pp];
    s.wu = w_p[(size_t)pp * 16 + (c >> 1)];
    const unsigned int* shp = esh_p + (size_t)pp * 5;
#pragma unroll
    for (int j = 0; j < 5; ++j) s.shd[j] = shp[j];
    const unsigned int* xp = x_p + (size_t)sidx * 160 + c;
    s.xd[0] = xp[0]; s.xd[1] = xp[32]; s.xd[2] = xp[64];
    s.xd[3] = xp[96]; s.xd[4] = xp[128];
    return s;
  };

  auto accum = [&](const Stage& s) {
    float wc = s.ok ? ((c & 1) ? bf_hi(s.wu) : bf_lo(s.wu)) : 0.f;
    f32x2 sh2[4];
    sh2[0] = (f32x2){bf_lo(s.shd[0]), bf_hi(s.shd[0])};
    sh2[1] = (f32x2){bf_lo(s.shd[1]), bf_hi(s.shd[1])};
    sh2[2] = (f32x2){bf_lo(s.shd[2]), bf_hi(s.shd[2])};
    sh2[3] = (f32x2){bf_lo(s.shd[3]), bf_hi(s.shd[3])};
    float sh8 = bf_lo(s.shd[4]);
    float xs[DD];
    xs[0] = bf_lo(s.xd[0]); xs[1] = bf_hi(s.xd[0]);
    xs[2] = bf_lo(s.xd[1]); xs[3] = bf_hi(s.xd[1]);
    xs[4] = bf_lo(s.xd[2]); xs[5] = bf_hi(s.xd[2]);
    xs[6] = bf_lo(s.xd[3]); xs[7] = bf_hi(s.xd[3]);
    xs[8] = bf_lo(s.xd[4]);
#pragma unroll
    for (int i = 0; i < DD; ++i) {
      float t = wc * xs[i];
      f32x2 t2 = (f32x2){t, t};
#pragma unroll
      for (int jp = 0; jp < 4; ++jp) Pp[i * 4 + jp] = t2 * sh2[jp] + Pp[i * 4 + jp];
      P8[i] += t * sh8;
    }
  };

  Stage A = loadStage(beg + h);
  Stage B = loadStage(beg + 2 + h);
  for (int p0 = beg; p0 < end; p0 += 4) {
    Stage Cs = loadStage(p0 + 4 + h);
    Stage Ds = loadStage(p0 + 6 + h);
    accum(A);
    accum(B);
    A = Cs;
    B = Ds;
  }

  f32x2 m2[4];
  float m8 = 0.f;
#pragma unroll
  for (int kp = 0; kp < 4; ++kp) m2[kp] = (f32x2){0.f, 0.f};
#pragma unroll
  for (int i = 0; i < DD; ++i) {
#pragma unroll
    for (int j = 0; j < DD; ++j) {
      float p = (j < 8) ? ((j & 1) ? Pp[i * 4 + (j >> 1)].y : Pp[i * 4 + (j >> 1)].x)
                        : P8[i];
      f32x2 p2 = (f32x2){p, p};
      const float* cgr = CG + i * 81 + j * DD;
#pragma unroll
      for (int kp = 0; kp < 4; ++kp) {
        f32x2 cg2 = (f32x2){cgr[2 * kp], cgr[2 * kp + 1]};
        m2[kp] = p2 * cg2 + m2[kp];
      }
      m8 += p * cgr[8];
    }
  }
  float m[DD];
  m[0] = m2[0].x; m[1] = m2[0].y;
  m[2] = m2[1].x; m[3] = m2[1].y;
  m[4] = m2[2].x; m[5] = m2[2].y;
  m[6] = m2[3].x; m[7] = m2[3].y;
  m[8] = m8;
#pragma unroll
  for (int k = 0; k < DD; ++k) m[k] += __shfl_xor(m[k], 32);
  if (h == 0) {
    float* mp = mpre + (size_t)wid * CD + c;
#pragma unroll
    for (int k = 0; k < DD; ++k) mp[k * 32] = m[k];
  }
}

// ---------------- fused output: persistent blocks, batch prefetch ----------------
__global__ __launch_bounds__(288, 1) void k_out(
    const float* __restrict__ attrs, const float* __restrict__ Wlin,
    const float* __restrict__ Wsc,
    float* __restrict__ out1, float* __restrict__ out2, int N) {
  __shared__ float smp[NB][CD];
  __shared__ float smt[NB][CD];
  __shared__ float sres1[NB * CD];
  __shared__ float sres2[NB * CD];
  int t = threadIdx.x;
  int g = t >> 5, q = t & 31;
  int l0 = blk_of(g);
  float wl[CC];
#pragma unroll
  for (int c = 0; c < CC; ++c) wl[c] = Wlin[l0 * 1024 + c * 32 + q];
  float ws0[CC], ws1[CC], ws2[CC], ws3[CC];
#pragma unroll
  for (int c = 0; c < CC; ++c) {
    ws0[c] = Wsc[0 * 3072 + l0 * 1024 + c * 32 + q];
    ws1[c] = Wsc[1 * 3072 + l0 * 1024 + c * 32 + q];
    ws2[c] = Wsc[2 * 3072 + l0 * 1024 + c * 32 + q];
    ws3[c] = Wsc[3 * 3072 + l0 * 1024 + c * 32 + q];
  }
  int nbat = (N + NB - 1) / NB;
  int b = blockIdx.x;
  float r[NB];
  if (b < nbat) {
#pragma unroll
    for (int nb = 0; nb < NB; ++nb) r[nb] = out2[(size_t)(b * NB + nb) * CD + t];
  }
  for (; b < nbat; b += gridDim.x) {
    int n0 = b * NB;
    __syncthreads();
#pragma unroll
    for (int nb = 0; nb < NB; ++nb) smp[nb][t] = r[nb];
    float4 av[NB];
#pragma unroll
    for (int nb = 0; nb < NB; ++nb) av[nb] = ((const float4*)attrs)[n0 + nb];
    __syncthreads();
    int b2 = b + gridDim.x;
    if (b2 < nbat) {
#pragma unroll
      for (int nb = 0; nb < NB; ++nb) r[nb] = out2[(size_t)(b2 * NB + nb) * CD + t];
    }
#pragma unroll
    for (int nb = 0; nb < NB; ++nb) {
      const float4* rowp = (const float4*)(smp[nb] + g * 32);
      float b0 = 0.f, b1 = 0.f;
#pragma unroll
      for (int c4 = 0; c4 < 8; ++c4) {
        float4 bb = rowp[c4];
        b0 += bb.x * wl[c4 * 4 + 0] + bb.y * wl[c4 * 4 + 1];
        b1 += bb.z * wl[c4 * 4 + 2] + bb.w * wl[c4 * 4 + 3];
      }
      float v = (b0 + b1) * (1.0f / 16.0f);
      smt[nb][t] = v;
      sres1[nb * CD + q * DD + g] = v;
    }
    __syncthreads();
#pragma unroll
    for (int nb = 0; nb < NB; ++nb) {
      const float4* rowp = (const float4*)(smt[nb] + g * 32);
      float z0 = 0.f, z1 = 0.f, z2 = 0.f, z3 = 0.f;
#pragma unroll
      for (int c4 = 0; c4 < 8; ++c4) {
        float4 bb = rowp[c4];
#pragma unroll
        for (int j = 0; j < 4; ++j) {
          float bv = (j == 0) ? bb.x : (j == 1) ? bb.y : (j == 2) ? bb.z : bb.w;
          int c = c4 * 4 + j;
          z0 += bv * ws0[c];
          z1 += bv * ws1[c];
          z2 += bv * ws2[c];
          z3 += bv * ws3[c];
        }
      }
      float4 a = av[nb];
      sres2[nb * CD + q * DD + g] = a.x * z0 + a.y * z1 + a.z * z2 + a.w * z3;
    }
    __syncthreads();
#pragma unroll
    for (int rr = 0; rr < (NB * 72) / 288; ++rr) {
      int s = rr * 288 + t;
      int nb = s / 72, idx = s - nb * 72;
      ((float4*)(out1 + (size_t)(n0 + nb) * CD))[idx] = ((const float4*)sres1)[s];
      ((float4*)(out2 + (size_t)(n0 + nb) * CD))[idx] = ((const float4*)sres2)[s];
    }
  }
}

extern "C" void kernel_launch(void* const* d_in, const int* in_sizes, int n_in,
                              void* d_out, int out_size, void* d_ws, size_t ws_size,
                              hipStream_t stream) {
  const float* nf    = (const float*)d_in[0];
  const float* attrs = (const float*)d_in[1];
  const float* ef    = (const float*)d_in[2];
  const float* esh   = (const float*)d_in[3];
  const float* cutv  = (const float*)d_in[4];
  const float* Wup   = (const float*)d_in[5];
  const float* W1    = (const float*)d_in[6];
  const float* W2    = (const float*)d_in[7];
  const float* W3    = (const float*)d_in[8];
  const float* Wlin  = (const float*)d_in[9];
  const float* Wsc   = (const float*)d_in[10];
  const float* CG    = (const float*)d_in[11];
  const int* esrc    = (const int*)d_in[12];
  const int* edst    = (const int*)d_in[13];
  int N = in_sizes[0] / CD;
  int E = in_sizes[12];
  float* out1 = (float*)d_out;
  float* out2 = out1 + (size_t)N * CD;   // doubles as the m_pre accumulator

  unsigned int* x_p   = (unsigned int*)d_ws;            // N*160 uint (bf16x2)
  unsigned int* w_p   = x_p + (size_t)N * 160;          // E*16 uint (dst-sorted, bf16x2)
  unsigned int* esh_p = w_p + (size_t)E * 16;           // E*5 uint (dst-sorted, bf16x2)
  int* deg     = (int*)(esh_p + (size_t)E * 5);         // N
  int* offs    = deg + N;                               // N+1
  int* cursor  = offs + N + 1;                          // N
  int* eidx    = cursor + N;                            // E
  int* srcs    = eidx + E;                              // E

  k_zero<<<(N + 255) / 256, 256, 0, stream>>>((float*)deg, N);
  k_hist<<<(E + 255) / 256, 256, 0, stream>>>(edst, deg, E);
  k_scan<<<1, 1024, 0, stream>>>(deg, offs, cursor, N);
  k_scatter<<<(E + 255) / 256, 256, 0, stream>>>(edst, esrc, esh, cursor, eidx, srcs, esh_p, E);
  k_linear_up<<<512, 288, 0, stream>>>(nf, Wup, x_p, N);
  k_mlp_mfma<<<4096, 64, 0, stream>>>(ef, cutv, W1, W2, W3, eidx, w_p, E);
  k_gather<<<(N + 3) / 4, 256, 0, stream>>>(x_p, w_p, esh_p, CG, offs, srcs, out2, N);
  k_out<<<512, 288, 0, stream>>>(attrs, Wlin, Wsc, out1, out2, N);
}

// Round 26
// 217.068 us; speedup vs baseline: 1.0206x; 1.0206x over previous
//
#include <hip/hip_runtime.h>
#include <cstdint>

#define CC 32
#define DD 9
#define CD 288   // C*D
#define BB 8
#define HH 64
#define ZZ 4
#define NB 8     // nodes per batch in node-side kernels

typedef __attribute__((ext_vector_type(8))) short bf16x8;
typedef __attribute__((ext_vector_type(4))) float f32x4;
typedef __attribute__((ext_vector_type(2))) float f32x2;

__device__ __forceinline__ float silu_f(float v) {
  return v / (1.0f + __expf(-v));
}

__device__ __forceinline__ int blk_of(int d) { return d == 0 ? 0 : (d < 4 ? 1 : 2); }

__device__ __forceinline__ unsigned int f2bf(float f) {   // round-to-nearest-even
  unsigned int u = __float_as_uint(f);
  return (u + 0x7fffu + ((u >> 16) & 1u)) >> 16;
}
__device__ __forceinline__ float bf_lo(unsigned int u) { return __uint_as_float(u << 16); }
__device__ __forceinline__ float bf_hi(unsigned int u) { return __uint_as_float(u & 0xffff0000u); }

__global__ __launch_bounds__(256) void k_zero(float* __restrict__ p, int n) {
  int i = blockIdx.x * 256 + threadIdx.x;
  if (i < n) p[i] = 0.0f;
}

// ---------------- CSR build ----------------
__global__ __launch_bounds__(256) void k_hist(const int* __restrict__ edst,
                                              int* __restrict__ deg, int E) {
  int e = blockIdx.x * 256 + threadIdx.x;
  if (e < E) atomicAdd(&deg[edst[e]], 1);
}

__global__ __launch_bounds__(1024) void k_scan(const int* __restrict__ deg,
                                               int* __restrict__ offs,
                                               int* __restrict__ cursor, int N) {
  __shared__ int part[1024];
  int t = threadIdx.x;
  int chunk = (N + 1023) >> 10;
  int base = t * chunk;
  int lim = N - base; if (lim > chunk) lim = chunk; if (lim < 0) lim = 0;
  int s = 0;
  for (int i = 0; i < lim; ++i) s += deg[base + i];
  part[t] = s;
  __syncthreads();
  for (int off = 1; off < 1024; off <<= 1) {
    int v = part[t];
    int u = (t >= off) ? part[t - off] : 0;
    __syncthreads();
    part[t] = v + u;
    __syncthreads();
  }
  int run = (t == 0) ? 0 : part[t - 1];
  for (int i = 0; i < lim; ++i) {
    offs[base + i] = run;
    cursor[base + i] = run;
    run += deg[base + i];
  }
  if (t == 1023) offs[N] = run;
}

// scatter + fused esh packing: eidx[pos], srcs[pos], esh_p[pos*5 + 0..4]
__global__ __launch_bounds__(256) void k_scatter(const int* __restrict__ edst,
                                                 const int* __restrict__ esrc,
                                                 const float* __restrict__ esh,
                                                 int* __restrict__ cursor,
                                                 int* __restrict__ eidx,
                                                 int* __restrict__ srcs,
                                                 unsigned int* __restrict__ esh_p, int E) {
  int e = blockIdx.x * 256 + threadIdx.x;
  if (e < E) {
    int d = edst[e];
    int pos = atomicAdd(&cursor[d], 1);
    eidx[pos] = e;
    srcs[pos] = esrc[e];
    const float* sp = esh + (size_t)e * 9;
    unsigned int* op = esh_p + (size_t)pos * 5;
#pragma unroll
    for (int jj = 0; jj < 5; ++jj) {
      unsigned int lo = f2bf(sp[2 * jj]);
      unsigned int hi = (jj < 4) ? f2bf(sp[2 * jj + 1]) : 0u;
      op[jj] = lo | (hi << 16);
    }
  }
}

// ---------------- linear_up: persistent blocks + register prefetch ----------------
__global__ __launch_bounds__(288, 1) void k_linear_up(
    const float* __restrict__ nf, const float* __restrict__ Wup,
    unsigned int* __restrict__ x_p, int N) {
  __shared__ float snf[NB][DD * 36];
  __shared__ float sval[NB][DD][CC];
  int t = threadIdx.x;
  int g = t >> 5, q = t & 31;
  int tc = t / 9, td = t - tc * 9;
  int l0 = blk_of(g);
  float wcol[CC];
#pragma unroll
  for (int c = 0; c < CC; ++c) wcol[c] = Wup[l0 * 1024 + c * 32 + q];
  int nbat = (N + NB - 1) / NB;
  int b = blockIdx.x;
  float r[NB];
  if (b < nbat) {
#pragma unroll
    for (int nb = 0; nb < NB; ++nb) {
      int n = b * NB + nb; if (n >= N) n = N - 1;
      r[nb] = nf[(size_t)n * CD + t];
    }
  }
  for (; b < nbat; b += gridDim.x) {
    int n0 = b * NB;
    __syncthreads();
#pragma unroll
    for (int nb = 0; nb < NB; ++nb) snf[nb][td * 36 + tc] = r[nb];
    __syncthreads();
    int b2 = b + gridDim.x;
    if (b2 < nbat) {
#pragma unroll
      for (int nb = 0; nb < NB; ++nb) {
        int n = b2 * NB + nb; if (n >= N) n = N - 1;
        r[nb] = nf[(size_t)n * CD + t];
      }
    }
#pragma unroll
    for (int nb = 0; nb < NB; ++nb) {
      const float4* rowp = (const float4*)(snf[nb] + g * 36);
      float a0 = 0.f, a1 = 0.f;
#pragma unroll
      for (int c4 = 0; c4 < 8; ++c4) {
        float4 bb = rowp[c4];
        a0 += bb.x * wcol[c4 * 4 + 0] + bb.y * wcol[c4 * 4 + 1];
        a1 += bb.z * wcol[c4 * 4 + 2] + bb.w * wcol[c4 * 4 + 3];
      }
      sval[nb][g][q] = a0 + a1;
    }
    __syncthreads();
#pragma unroll
    for (int it = 0; it < 5; ++it) {
      int idx = it * 288 + t;
      if (idx < NB * 160) {
        int nb = idx / 160, rr = idx - nb * 160;
        int p = rr >> 5, c = rr & 31;
        if (n0 + nb < N) {
          unsigned int lo = f2bf(sval[nb][2 * p][c]);
          unsigned int hi = (p < 4) ? f2bf(sval[nb][2 * p + 1][c]) : 0u;
          x_p[(size_t)(n0 + nb) * 160 + rr] = lo | (hi << 16);
        }
      }
    }
  }
}

// ---------------- radial MLP: ALL THREE layers via MFMA; one wave = 64 edges ----------------
__global__ __launch_bounds__(64) void k_mlp_mfma(
    const float* __restrict__ ef, const float* __restrict__ cut,
    const float* __restrict__ W1, const float* __restrict__ W2,
    const float* __restrict__ W3, const int* __restrict__ eidx,
    unsigned int* __restrict__ w_p, int E) {
  __shared__ ushort efbuf[2048];   // 4KB B-frag for layer1
  __shared__ ushort buf[4096];     // 8KB h1 then h2
  __shared__ float scut[64];
  int l = threadIdx.x;
  int h = l >> 4, li = l & 15;
  bf16x8 A1[4];
#pragma unroll
  for (int qm = 0; qm < 4; ++qm)
#pragma unroll
    for (int j = 0; j < 8; ++j)
      A1[qm][j] = (h == 0) ? (short)f2bf(W1[j * HH + 16 * qm + li]) : (short)0;
  bf16x8 A2[4][2];
#pragma unroll
  for (int qm = 0; qm < 4; ++qm)
#pragma unroll
    for (int kb = 0; kb < 2; ++kb)
#pragma unroll
      for (int j = 0; j < 8; ++j)
        A2[qm][kb][j] = (short)f2bf(W2[(32 * kb + 8 * h + j) * HH + 16 * qm + li]);
  bf16x8 A3[2][2];
#pragma unroll
  for (int cm = 0; cm < 2; ++cm)
#pragma unroll
    for (int kb = 0; kb < 2; ++kb)
#pragma unroll
      for (int j = 0; j < 8; ++j)
        A3[cm][kb][j] = (short)f2bf(W3[(32 * kb + 8 * h + j) * CC + 16 * cm + li]);
#pragma unroll
  for (int i = 0; i < 16; ++i) ((unsigned int*)efbuf)[i * 64 + l] = 0u;

  int ntile = E >> 6;
  for (int tile = blockIdx.x; tile < ntile; tile += gridDim.x) {
    int pos = tile * 64 + l;
    int eo = eidx[pos];
    const float4* efp = (const float4*)(ef + (size_t)eo * BB);
    float4 efa = efp[0];
    float4 efb = efp[1];
    scut[l] = cut[eo];
    {
      unsigned int d0 = f2bf(efa.x) | (f2bf(efa.y) << 16);
      unsigned int d1 = f2bf(efa.z) | (f2bf(efa.w) << 16);
      unsigned int d2 = f2bf(efb.x) | (f2bf(efb.y) << 16);
      unsigned int d3 = f2bf(efb.z) | (f2bf(efb.w) << 16);
      *(uint4*)&efbuf[(((l >> 4) * 4) * 16 + (l & 15)) * 8] = make_uint4(d0, d1, d2, d3);
    }
    f32x4 acc1[4][4];
#pragma unroll
    for (int qm = 0; qm < 4; ++qm)
#pragma unroll
      for (int nb = 0; nb < 4; ++nb) acc1[qm][nb] = (f32x4){0.f, 0.f, 0.f, 0.f};
#pragma unroll
    for (int nb = 0; nb < 4; ++nb) {
      bf16x8 Bf = *(const bf16x8*)&efbuf[((nb * 4 + h) * 16 + li) * 8];
#pragma unroll
      for (int qm = 0; qm < 4; ++qm)
        acc1[qm][nb] = __builtin_amdgcn_mfma_f32_16x16x32_bf16(
            A1[qm], Bf, acc1[qm][nb], 0, 0, 0);
    }
#pragma unroll
    for (int qm = 0; qm < 4; ++qm)
#pragma unroll
      for (int nb = 0; nb < 4; ++nb) {
        float v0 = silu_f(acc1[qm][nb][0]);
        float v1 = silu_f(acc1[qm][nb][1]);
        float v2 = silu_f(acc1[qm][nb][2]);
        float v3 = silu_f(acc1[qm][nb][3]);
        unsigned int lo = f2bf(v0) | (f2bf(v1) << 16);
        unsigned int hi = f2bf(v2) | (f2bf(v3) << 16);
        int G = (nb * 2 + (qm >> 1)) * 4 + ((2 * qm + (h >> 1)) & 3);
        *(uint2*)&buf[(G * 16 + li) * 8 + (h & 1) * 4] = make_uint2(lo, hi);
      }
    f32x4 acc2[4][4];
#pragma unroll
    for (int qm = 0; qm < 4; ++qm)
#pragma unroll
      for (int nb = 0; nb < 4; ++nb) acc2[qm][nb] = (f32x4){0.f, 0.f, 0.f, 0.f};
#pragma unroll
    for (int nb = 0; nb < 4; ++nb)
#pragma unroll
      for (int kb = 0; kb < 2; ++kb) {
        int F = (nb * 2 + kb) * 4 + h;
        bf16x8 Bf = *(const bf16x8*)&buf[(F * 16 + li) * 8];
#pragma unroll
        for (int qm = 0; qm < 4; ++qm)
          acc2[qm][nb] = __builtin_amdgcn_mfma_f32_16x16x32_bf16(
              A2[qm][kb], Bf, acc2[qm][nb], 0, 0, 0);
      }
#pragma unroll
    for (int qm = 0; qm < 4; ++qm)
#pragma unroll
      for (int nb = 0; nb < 4; ++nb) {
        float v0 = silu_f(acc2[qm][nb][0]);
        float v1 = silu_f(acc2[qm][nb][1]);
        float v2 = silu_f(acc2[qm][nb][2]);
        float v3 = silu_f(acc2[qm][nb][3]);
        unsigned int lo = f2bf(v0) | (f2bf(v1) << 16);
        unsigned int hi = f2bf(v2) | (f2bf(v3) << 16);
        int G = (nb * 2 + (qm >> 1)) * 4 + ((2 * qm + (h >> 1)) & 3);
        *(uint2*)&buf[(G * 16 + li) * 8 + (h & 1) * 4] = make_uint2(lo, hi);
      }
    f32x4 acc3[2][4];
#pragma unroll
    for (int cm = 0; cm < 2; ++cm)
#pragma unroll
      for (int nb = 0; nb < 4; ++nb) acc3[cm][nb] = (f32x4){0.f, 0.f, 0.f, 0.f};
#pragma unroll
    for (int nb = 0; nb < 4; ++nb)
#pragma unroll
      for (int kb = 0; kb < 2; ++kb) {
        int G = (nb * 2 + kb) * 4 + h;
        bf16x8 Bf = *(const bf16x8*)&buf[(G * 16 + li) * 8];
#pragma unroll
        for (int cm = 0; cm < 2; ++cm)
          acc3[cm][nb] = __builtin_amdgcn_mfma_f32_16x16x32_bf16(
              A3[cm][kb], Bf, acc3[cm][nb], 0, 0, 0);
      }
#pragma unroll
    for (int nb = 0; nb < 4; ++nb) {
      float cv = scut[16 * nb + li];
#pragma unroll
      for (int cm = 0; cm < 2; ++cm) {
        unsigned int lo = f2bf(acc3[cm][nb][0] * cv) | (f2bf(acc3[cm][nb][1] * cv) << 16);
        unsigned int hi = f2bf(acc3[cm][nb][2] * cv) | (f2bf(acc3[cm][nb][3] * cv) << 16);
        *(uint2*)&w_p[(size_t)(tile * 64 + 16 * nb + li) * 16 + 8 * cm + 2 * h] =
            make_uint2(lo, hi);
      }
    }
  }
}

// ---------------- gather v6 (best): pipelined + packed-f32 math ----------------
__global__ __launch_bounds__(256) void k_gather(
    const unsigned int* __restrict__ x_p, const unsigned int* __restrict__ w_p,
    const unsigned int* __restrict__ esh_p, const float* __restrict__ CG,
    const int* __restrict__ offs, const int* __restrict__ srcs,
    float* __restrict__ mpre, int N) {
  int wid = (blockIdx.x * 256 + threadIdx.x) >> 6;
  if (wid >= N) return;
  int lane = threadIdx.x & 63;
  int h = lane >> 5, c = lane & 31;
  int beg = offs[wid], end = offs[wid + 1];
  f32x2 Pp[36];
  float P8[9];
#pragma unroll
  for (int i = 0; i < 36; ++i) Pp[i] = (f32x2){0.f, 0.f};
#pragma unroll
  for (int i = 0; i < 9; ++i) P8[i] = 0.f;

  bool okc;
  unsigned int wu_c;
  unsigned int shd_c[5];
  unsigned int xd_c[5];
  {
    int p = beg + h;
    okc = p < end;
    int pp = okc ? p : beg;
    int s = srcs[pp];
    wu_c = w_p[(size_t)pp * 16 + (c >> 1)];
    const unsigned int* shp = esh_p + (size_t)pp * 5;
#pragma unroll
    for (int j = 0; j < 5; ++j) shd_c[j] = shp[j];
    const unsigned int* xp = x_p + (size_t)s * 160 + c;
    xd_c[0] = xp[0]; xd_c[1] = xp[32]; xd_c[2] = xp[64]; xd_c[3] = xp[96]; xd_c[4] = xp[128];
  }

  for (int p0 = beg; p0 < end; p0 += 2) {
    int pn = p0 + 2 + h;
    bool okn = pn < end;
    int ppn = okn ? pn : beg;
    int s_n = srcs[ppn];
    unsigned int wu_n = w_p[(size_t)ppn * 16 + (c >> 1)];
    unsigned int shd_n[5];
    {
      const unsigned int* shp = esh_p + (size_t)ppn * 5;
#pragma unroll
      for (int j = 0; j < 5; ++j) shd_n[j] = shp[j];
    }
    unsigned int xd_n[5];
    {
      const unsigned int* xp = x_p + (size_t)s_n * 160 + c;
      xd_n[0] = xp[0]; xd_n[1] = xp[32]; xd_n[2] = xp[64]; xd_n[3] = xp[96]; xd_n[4] = xp[128];
    }
    float wc = okc ? ((c & 1) ? bf_hi(wu_c) : bf_lo(wu_c)) : 0.f;
    f32x2 sh2[4];
    sh2[0] = (f32x2){bf_lo(shd_c[0]), bf_hi(shd_c[0])};
    sh2[1] = (f32x2){bf_lo(shd_c[1]), bf_hi(shd_c[1])};
    sh2[2] = (f32x2){bf_lo(shd_c[2]), bf_hi(shd_c[2])};
    sh2[3] = (f32x2){bf_lo(shd_c[3]), bf_hi(shd_c[3])};
    float sh8 = bf_lo(shd_c[4]);
    float xs[DD];
    xs[0] = bf_lo(xd_c[0]); xs[1] = bf_hi(xd_c[0]);
    xs[2] = bf_lo(xd_c[1]); xs[3] = bf_hi(xd_c[1]);
    xs[4] = bf_lo(xd_c[2]); xs[5] = bf_hi(xd_c[2]);
    xs[6] = bf_lo(xd_c[3]); xs[7] = bf_hi(xd_c[3]);
    xs[8] = bf_lo(xd_c[4]);
#pragma unroll
    for (int i = 0; i < DD; ++i) {
      float t = wc * xs[i];
      f32x2 t2 = (f32x2){t, t};
#pragma unroll
      for (int jp = 0; jp < 4; ++jp) Pp[i * 4 + jp] = t2 * sh2[jp] + Pp[i * 4 + jp];
      P8[i] += t * sh8;
    }
    okc = okn;
    wu_c = wu_n;
#pragma unroll
    for (int j = 0; j < 5; ++j) { shd_c[j] = shd_n[j]; xd_c[j] = xd_n[j]; }
  }

  f32x2 m2[4];
  float m8 = 0.f;
#pragma unroll
  for (int kp = 0; kp < 4; ++kp) m2[kp] = (f32x2){0.f, 0.f};
#pragma unroll
  for (int i = 0; i < DD; ++i) {
#pragma unroll
    for (int j = 0; j < DD; ++j) {
      float p = (j < 8) ? ((j & 1) ? Pp[i * 4 + (j >> 1)].y : Pp[i * 4 + (j >> 1)].x)
                        : P8[i];
      f32x2 p2 = (f32x2){p, p};
      const float* cgr = CG + i * 81 + j * DD;
#pragma unroll
      for (int kp = 0; kp < 4; ++kp) {
        f32x2 cg2 = (f32x2){cgr[2 * kp], cgr[2 * kp + 1]};
        m2[kp] = p2 * cg2 + m2[kp];
      }
      m8 += p * cgr[8];
    }
  }
  float m[DD];
  m[0] = m2[0].x; m[1] = m2[0].y;
  m[2] = m2[1].x; m[3] = m2[1].y;
  m[4] = m2[2].x; m[5] = m2[2].y;
  m[6] = m2[3].x; m[7] = m2[3].y;
  m[8] = m8;
#pragma unroll
  for (int k = 0; k < DD; ++k) m[k] += __shfl_xor(m[k], 32);
  if (h == 0) {
    float* mp = mpre + (size_t)wid * CD + c;
#pragma unroll
    for (int k = 0; k < DD; ++k) mp[k * 32] = m[k];
  }
}

// ---------------- fused output: persistent blocks, batch prefetch ----------------
__global__ __launch_bounds__(288, 1) void k_out(
    const float* __restrict__ attrs, const float* __restrict__ Wlin,
    const float* __restrict__ Wsc,
    float* __restrict__ out1, float* __restrict__ out2, int N) {
  __shared__ float smp[NB][CD];
  __shared__ float smt[NB][CD];
  __shared__ float sres1[NB * CD];
  __shared__ float sres2[NB * CD];
  int t = threadIdx.x;
  int g = t >> 5, q = t & 31;
  int l0 = blk_of(g);
  float wl[CC];
#pragma unroll
  for (int c = 0; c < CC; ++c) wl[c] = Wlin[l0 * 1024 + c * 32 + q];
  float ws0[CC], ws1[CC], ws2[CC], ws3[CC];
#pragma unroll
  for (int c = 0; c < CC; ++c) {
    ws0[c] = Wsc[0 * 3072 + l0 * 1024 + c * 32 + q];
    ws1[c] = Wsc[1 * 3072 + l0 * 1024 + c * 32 + q];
    ws2[c] = Wsc[2 * 3072 + l0 * 1024 + c * 32 + q];
    ws3[c] = Wsc[3 * 3072 + l0 * 1024 + c * 32 + q];
  }
  int nbat = (N + NB - 1) / NB;
  int b = blockIdx.x;
  float r[NB];
  if (b < nbat) {
#pragma unroll
    for (int nb = 0; nb < NB; ++nb) r[nb] = out2[(size_t)(b * NB + nb) * CD + t];
  }
  for (; b < nbat; b += gridDim.x) {
    int n0 = b * NB;
    __syncthreads();
#pragma unroll
    for (int nb = 0; nb < NB; ++nb) smp[nb][t] = r[nb];
    float4 av[NB];
#pragma unroll
    for (int nb = 0; nb < NB; ++nb) av[nb] = ((const float4*)attrs)[n0 + nb];
    __syncthreads();
    int b2 = b + gridDim.x;
    if (b2 < nbat) {
#pragma unroll
      for (int nb = 0; nb < NB; ++nb) r[nb] = out2[(size_t)(b2 * NB + nb) * CD + t];
    }
#pragma unroll
    for (int nb = 0; nb < NB; ++nb) {
      const float4* rowp = (const float4*)(smp[nb] + g * 32);
      float b0 = 0.f, b1 = 0.f;
#pragma unroll
      for (int c4 = 0; c4 < 8; ++c4) {
        float4 bb = rowp[c4];
        b0 += bb.x * wl[c4 * 4 + 0] + bb.y * wl[c4 * 4 + 1];
        b1 += bb.z * wl[c4 * 4 + 2] + bb.w * wl[c4 * 4 + 3];
      }
      float v = (b0 + b1) * (1.0f / 16.0f);
      smt[nb][t] = v;
      sres1[nb * CD + q * DD + g] = v;
    }
    __syncthreads();
#pragma unroll
    for (int nb = 0; nb < NB; ++nb) {
      const float4* rowp = (const float4*)(smt[nb] + g * 32);
      float z0 = 0.f, z1 = 0.f, z2 = 0.f, z3 = 0.f;
#pragma unroll
      for (int c4 = 0; c4 < 8; ++c4) {
        float4 bb = rowp[c4];
#pragma unroll
        for (int j = 0; j < 4; ++j) {
          float bv = (j == 0) ? bb.x : (j == 1) ? bb.y : (j == 2) ? bb.z : bb.w;
          int c = c4 * 4 + j;
          z0 += bv * ws0[c];
          z1 += bv * ws1[c];
          z2 += bv * ws2[c];
          z3 += bv * ws3[c];
        }
      }
      float4 a = av[nb];
      sres2[nb * CD + q * DD + g] = a.x * z0 + a.y * z1 + a.z * z2 + a.w * z3;
    }
    __syncthreads();
#pragma unroll
    for (int rr = 0; rr < (NB * 72) / 288; ++rr) {
      int s = rr * 288 + t;
      int nb = s / 72, idx = s - nb * 72;
      ((float4*)(out1 + (size_t)(n0 + nb) * CD))[idx] = ((const float4*)sres1)[s];
      ((float4*)(out2 + (size_t)(n0 + nb) * CD))[idx] = ((const float4*)sres2)[s];
    }
  }
}

extern "C" void kernel_launch(void* const* d_in, const int* in_sizes, int n_in,
                              void* d_out, int out_size, void* d_ws, size_t ws_size,
                              hipStream_t stream) {
  const float* nf    = (const float*)d_in[0];
  const float* attrs = (const float*)d_in[1];
  const float* ef    = (const float*)d_in[2];
  const float* esh   = (const float*)d_in[3];
  const float* cutv  = (const float*)d_in[4];
  const float* Wup   = (const float*)d_in[5];
  const float* W1    = (const float*)d_in[6];
  const float* W2    = (const float*)d_in[7];
  const float* W3    = (const float*)d_in[8];
  const float* Wlin  = (const float*)d_in[9];
  const float* Wsc   = (const float*)d_in[10];
  const float* CG    = (const float*)d_in[11];
  const int* esrc    = (const int*)d_in[12];
  const int* edst    = (const int*)d_in[13];
  int N = in_sizes[0] / CD;
  int E = in_sizes[12];
  float* out1 = (float*)d_out;
  float* out2 = out1 + (size_t)N * CD;   // doubles as the m_pre accumulator

  unsigned int* x_p   = (unsigned int*)d_ws;            // N*160 uint (bf16x2)
  unsigned int* w_p   = x_p + (size_t)N * 160;          // E*16 uint (dst-sorted, bf16x2)
  unsigned int* esh_p = w_p + (size_t)E * 16;           // E*5 uint (dst-sorted, bf16x2)
  int* deg     = (int*)(esh_p + (size_t)E * 5);         // N
  int* offs    = deg + N;                               // N+1
  int* cursor  = offs + N + 1;                          // N
  int* eidx    = cursor + N;                            // E
  int* srcs    = eidx + E;                              // E

  k_zero<<<(N + 255) / 256, 256, 0, stream>>>((float*)deg, N);
  k_hist<<<(E + 255) / 256, 256, 0, stream>>>(edst, deg, E);
  k_scan<<<1, 1024, 0, stream>>>(deg, offs, cursor, N);
  k_scatter<<<(E + 255) / 256, 256, 0, stream>>>(edst, esrc, esh, cursor, eidx, srcs, esh_p, E);
  k_linear_up<<<512, 288, 0, stream>>>(nf, Wup, x_p, N);
  k_mlp_mfma<<<4096, 64, 0, stream>>>(ef, cutv, W1, W2, W3, eidx, w_p, E);
  k_gather<<<(N + 3) / 4, 256, 0, stream>>>(x_p, w_p, esh_p, CG, offs, srcs, out2, N);
  k_out<<<512, 288, 0, stream>>>(attrs, Wlin, Wsc, out1, out2, N);
}